// Round 9
// baseline (150.013 us; speedup 1.0000x reference)
//
#include <hip/hip_runtime.h>
#include <hip/hip_bf16.h>

// Encoding layer (Deep-TEN). B=16, D=128, K=32, N=H*W=4096.
// E[b,k,d] = sum_n A[b,n,k]*(X[b,n,d]-C[k,d]),  A = softmax_k(scale[k]*||X-C_k||^2)
// x layout: (B, D, H, W) -> X[b,n,d] = x[d*NTOT + n]
//
// R9: fuse the reduction into k1 ("last block per b reduces"): after the
// coalesced partial store, __threadfence (device-scope release, crosses
// per-XCD L2) + atomicAdd on a per-b counter in d_ws; the 32nd block
// acquires + sums the 32 partials -> d_out. Kills the second launch and its
// full-grid serialization (~5us). Counters re-zeroed each call via
// hipMemsetAsync (graph-safe). Fallback to R8 two-kernel path if ws too small.

#define D_   128
#define K_   32
#define NPB  64
#define NTOT 4096
#define PART_BYTES (512 * K_ * D_ * 4)   // 8 MB of partials

typedef __attribute__((ext_vector_type(8))) short bf16x8;
typedef __attribute__((ext_vector_type(4))) float f32x4;
typedef __attribute__((ext_vector_type(4))) short short4v;

__device__ __forceinline__ short f2b(float f) {
  return (short)__builtin_bit_cast(unsigned short, __float2bfloat16(f));
}

template <int FUSED>
__global__ __launch_bounds__(256, 2) void enc_kernel(
    const float* __restrict__ x,
    const float* __restrict__ cw,
    const float* __restrict__ scale,
    float* __restrict__ ws,
    int* __restrict__ cnt,               // per-b arrival counters (zeroed)
    float* __restrict__ out)
{
  __shared__ __align__(16) short sNb[NPB * D_];  // bf16 X [n][d] swz, 16 KB
  __shared__ __align__(16) short sDb[D_ * NPB];  // bf16 X [d][n] swz, 16 KB
  __shared__ __align__(16) short sAb[K_ * NPB];  // bf16 A [k][n] swz, 4 KB
  __shared__ __align__(16) float sX2w[NPB * 4];
  __shared__ float sasum[K_];
  __shared__ int sIsLast;

  const int t  = threadIdx.x;
  const int w  = t >> 6;
  const int l  = t & 63;
  const int lr = l & 15;
  const int lg = l >> 4;
  const int b  = blockIdx.x >> 5;               // 32 blocks per b
  const int nbase = (blockIdx.x & 31) * 128;    // 2 tiles of 64

  const int n4s = t & 15;
  const int d0  = (t >> 4) * 8;
  const float* xb = x + (size_t)b * D_ * NTOT + nbase;

  // ---- resident pass1 B-frags: C^T bf16 + exact c2 (C first: vmcnt is FIFO,
  // C drains early so its VALU overlaps the x-tile flight) ----
  bf16x8 bC[2][4];
  float c2p0 = 0.f, c2p1 = 0.f;
  #pragma unroll
  for (int kt = 0; kt < 2; ++kt) {
    const float* crow = cw + (lr + 16 * kt) * D_ + lg * 8;
    #pragma unroll
    for (int s = 0; s < 4; ++s) {
      float4 v0 = *reinterpret_cast<const float4*>(crow + 32 * s);
      float4 v1 = *reinterpret_cast<const float4*>(crow + 32 * s + 4);
      float vv[8] = {v0.x, v0.y, v0.z, v0.w, v1.x, v1.y, v1.z, v1.w};
      bf16x8 f;
      float cs = 0.f;
      #pragma unroll
      for (int j = 0; j < 8; ++j) { f[j] = f2b(vv[j]); cs = fmaf(vv[j], vv[j], cs); }
      bC[kt][s] = f;
      if (kt == 0) c2p0 += cs; else c2p1 += cs;
    }
  }
  c2p0 += __shfl_xor(c2p0, 16); c2p0 += __shfl_xor(c2p0, 32);
  c2p1 += __shfl_xor(c2p1, 16); c2p1 += __shfl_xor(c2p1, 32);
  const float sc0 = scale[lr];
  const float sc1 = scale[lr + 16];

  // ---- prologue: load + stage tile 0 ----
  float4 xs[8];
  #pragma unroll
  for (int j = 0; j < 8; ++j)
    xs[j] = *reinterpret_cast<const float4*>(xb + (size_t)(d0 + j) * NTOT + n4s * 4);
  if (t < K_) sasum[t] = 0.0f;

  #define STAGE_TILE()                                                        \
  {                                                                           \
    short xb16[8][4];                                                         \
    _Pragma("unroll")                                                         \
    for (int j = 0; j < 8; ++j) {                                             \
      xb16[j][0] = f2b(xs[j].x); xb16[j][1] = f2b(xs[j].y);                   \
      xb16[j][2] = f2b(xs[j].z); xb16[j][3] = f2b(xs[j].w);                   \
    }                                                                         \
    float p2[4] = {0.f, 0.f, 0.f, 0.f};                                       \
    _Pragma("unroll")                                                         \
    for (int j = 0; j < 8; ++j) {                                             \
      p2[0] = fmaf(xs[j].x, xs[j].x, p2[0]);                                  \
      p2[1] = fmaf(xs[j].y, xs[j].y, p2[1]);                                  \
      p2[2] = fmaf(xs[j].z, xs[j].z, p2[2]);                                  \
      p2[3] = fmaf(xs[j].w, xs[j].w, p2[3]);                                  \
    }                                                                         \
    _Pragma("unroll")                                                         \
    for (int i = 0; i < 4; ++i) {                                             \
      p2[i] += __shfl_xor(p2[i], 16);                                         \
      p2[i] += __shfl_xor(p2[i], 32);                                         \
    }                                                                         \
    if (lg == 0) {                                                            \
      _Pragma("unroll")                                                       \
      for (int i = 0; i < 4; ++i) sX2w[(n4s * 4 + i) * 4 + w] = p2[i];        \
    }                                                                         \
    _Pragma("unroll")                                                         \
    for (int i = 0; i < 4; ++i) {                                             \
      int n = n4s * 4 + i;                                                    \
      bf16x8 pk;                                                              \
      _Pragma("unroll")                                                       \
      for (int j = 0; j < 8; ++j) pk[j] = xb16[j][i];                         \
      int phys = ((d0 >> 3) ^ (n & 15)) & 15;                                 \
      *reinterpret_cast<bf16x8*>(&sNb[n * D_ + phys * 8]) = pk;               \
    }                                                                         \
    _Pragma("unroll")                                                         \
    for (int j = 0; j < 8; ++j) {                                             \
      int d = d0 + j;                                                         \
      int phys = ((n4s >> 1) ^ (d & 7) ^ ((d >> 3) & 7)) & 7;                 \
      short4v pk4 = {xb16[j][0], xb16[j][1], xb16[j][2], xb16[j][3]};         \
      *reinterpret_cast<short4v*>(&sDb[d * NPB + phys * 8 + (n4s & 1) * 4]) = pk4; \
    }                                                                         \
  }

  STAGE_TILE();
  __syncthreads();

  const int m0 = w * 16;
  const int nrow = m0 + lr;
  f32x4 acc[2][2];
  float asvT[2][4];
  #pragma unroll
  for (int mt = 0; mt < 2; ++mt) {
    #pragma unroll
    for (int dti = 0; dti < 2; ++dti) acc[mt][dti] = (f32x4){0.f, 0.f, 0.f, 0.f};
    #pragma unroll
    for (int r = 0; r < 4; ++r) asvT[mt][r] = 0.f;
  }

  #pragma unroll
  for (int tile = 0; tile < 2; ++tile) {
    if (tile == 0) {                     // prefetch tile1: in flight under compute
      #pragma unroll
      for (int j = 0; j < 8; ++j)
        xs[j] = *reinterpret_cast<const float4*>(
            xb + 64 + (size_t)(d0 + j) * NTOT + n4s * 4);
    }

    // ---- pass 1: xc tile [16n x 32k] per wave ----
    f32x4 p0 = {0.f, 0.f, 0.f, 0.f}, p1 = {0.f, 0.f, 0.f, 0.f};
    #pragma unroll
    for (int s = 0; s < 4; ++s) {
      int dblk = 4 * s + lg;
      bf16x8 af = *reinterpret_cast<const bf16x8*>(
          &sNb[nrow * D_ + ((dblk ^ lr) & 15) * 8]);
      p0 = __builtin_amdgcn_mfma_f32_16x16x32_bf16(af, bC[0][s], p0, 0, 0, 0);
      p1 = __builtin_amdgcn_mfma_f32_16x16x32_bf16(af, bC[1][s], p1, 0, 0, 0);
    }
    float x2r[4];
    #pragma unroll
    for (int r = 0; r < 4; ++r) {
      float4 v = *reinterpret_cast<const float4*>(&sX2w[(m0 + lg * 4 + r) * 4]);
      x2r[r] = (v.x + v.y) + (v.z + v.w);
    }

    // ---- softmax over K=32 in-register ----
    float a0[4], a1[4], mr[4], sr[4];
    #pragma unroll
    for (int r = 0; r < 4; ++r) {
      float sl0 = sc0 * (x2r[r] - 2.f * p0[r] + c2p0);
      float sl1 = sc1 * (x2r[r] - 2.f * p1[r] + c2p1);
      a0[r] = sl0; a1[r] = sl1;
      mr[r] = fmaxf(sl0, sl1);
    }
    #pragma unroll
    for (int dlt = 1; dlt <= 8; dlt <<= 1)
      #pragma unroll
      for (int r = 0; r < 4; ++r) mr[r] = fmaxf(mr[r], __shfl_xor(mr[r], dlt));
    #pragma unroll
    for (int r = 0; r < 4; ++r) {
      a0[r] = __expf(a0[r] - mr[r]);
      a1[r] = __expf(a1[r] - mr[r]);
      sr[r] = a0[r] + a1[r];
    }
    #pragma unroll
    for (int dlt = 1; dlt <= 8; dlt <<= 1)
      #pragma unroll
      for (int r = 0; r < 4; ++r) sr[r] += __shfl_xor(sr[r], dlt);
    #pragma unroll
    for (int r = 0; r < 4; ++r) {
      float inv = 1.0f / sr[r];
      a0[r] *= inv; a1[r] *= inv;
    }

    // ---- block asum + A -> bf16 LDS tile ----
    float as0 = a0[0] + a0[1] + a0[2] + a0[3];
    float as1 = a1[0] + a1[1] + a1[2] + a1[3];
    as0 += __shfl_xor(as0, 16); as0 += __shfl_xor(as0, 32);
    as1 += __shfl_xor(as1, 16); as1 += __shfl_xor(as1, 32);
    if (lg == 0) {
      atomicAdd(&sasum[lr], as0);
      atomicAdd(&sasum[lr + 16], as1);
    }
    #pragma unroll
    for (int r = 0; r < 4; ++r) {
      int n = m0 + lg * 4 + r;
      sAb[lr * 64 + (n ^ ((lr & 7) << 3))] = f2b(a0[r]);
      sAb[(lr + 16) * 64 + (n ^ (((lr + 16) & 7) << 3))] = f2b(a1[r]);
    }
    __syncthreads();

    // ---- pass 2 accumulate: E += A^T X ----
    bf16x8 aA[2][2];
    #pragma unroll
    for (int mt = 0; mt < 2; ++mt) {
      int k = mt * 16 + lr;
      #pragma unroll
      for (int s = 0; s < 2; ++s) {
        int nb = 32 * s + lg * 8;
        aA[mt][s] = *reinterpret_cast<const bf16x8*>(
            &sAb[k * 64 + (nb ^ ((k & 7) << 3))]);
      }
    }
    #pragma unroll
    for (int mt = 0; mt < 2; ++mt)
      #pragma unroll
      for (int r = 0; r < 4; ++r) asvT[mt][r] += sasum[mt * 16 + lg * 4 + r];
    #pragma unroll
    for (int s = 0; s < 2; ++s) {
      #pragma unroll
      for (int dti = 0; dti < 2; ++dti) {
        int d = (2 * w + dti) * 16 + lr;
        int phys = (((4 * s + lg) ^ (d & 7) ^ ((d >> 3) & 7)) & 7);
        bf16x8 bf = *reinterpret_cast<const bf16x8*>(&sDb[d * NPB + phys * 8]);
        acc[0][dti] = __builtin_amdgcn_mfma_f32_16x16x32_bf16(aA[0][s], bf, acc[0][dti], 0, 0, 0);
        acc[1][dti] = __builtin_amdgcn_mfma_f32_16x16x32_bf16(aA[1][s], bf, acc[1][dti], 0, 0, 0);
      }
    }
    __syncthreads();                      // LDS free for next tile

    if (tile == 0) {
      if (t < K_) sasum[t] = 0.0f;
      STAGE_TILE();
      __syncthreads();
    }
  }

  // ---- epilogue: -asum*C correction + plain coalesced store to workspace ----
  float* wp = ws + (size_t)blockIdx.x * (K_ * D_);
  #pragma unroll
  for (int mt = 0; mt < 2; ++mt)
    #pragma unroll
    for (int dti = 0; dti < 2; ++dti) {
      int d = (2 * w + dti) * 16 + lr;
      #pragma unroll
      for (int r = 0; r < 4; ++r) {
        int k = mt * 16 + lg * 4 + r;
        wp[k * D_ + d] = acc[mt][dti][r] - asvT[mt][r] * cw[k * D_ + d];
      }
    }

  if (!FUSED) return;

  // ---- fused reduce: release, count arrivals, 32nd block for b reduces ----
  __threadfence();                        // device-scope release (crosses XCD L2)
  __syncthreads();
  if (t == 0) sIsLast = (atomicAdd(&cnt[b], 1) == 31);
  __syncthreads();
  if (!sIsLast) return;
  __threadfence();                        // acquire

  const float4* base = reinterpret_cast<const float4*>(ws) + (size_t)b * 32 * 1024;
  float4* ob = reinterpret_cast<float4*>(out) + (size_t)b * 1024;
  #pragma unroll
  for (int qi = 0; qi < 4; ++qi) {
    int q = qi * 256 + t;
    float4 s = {0.f, 0.f, 0.f, 0.f};
    #pragma unroll 8
    for (int p = 0; p < 32; ++p) {
      float4 v = base[(size_t)p * 1024 + q];
      s.x += v.x; s.y += v.y; s.z += v.z; s.w += v.w;
    }
    ob[q] = s;
  }
}

// fallback reduce (only used if ws can't hold the counters)
__global__ __launch_bounds__(256) void reduce_kernel(
    const float* __restrict__ ws, float* __restrict__ out)
{
  int g = blockIdx.x * 256 + threadIdx.x;
  int b = g >> 10;
  int q = g & 1023;
  const float4* base = reinterpret_cast<const float4*>(ws) + (size_t)b * 32 * 1024 + q;
  float4 s = {0.f, 0.f, 0.f, 0.f};
  #pragma unroll
  for (int t = 0; t < 32; ++t) {
    float4 v = base[(size_t)t * 1024];
    s.x += v.x; s.y += v.y; s.z += v.z; s.w += v.w;
  }
  reinterpret_cast<float4*>(out)[g] = s;
}

extern "C" void kernel_launch(void* const* d_in, const int* in_sizes, int n_in,
                              void* d_out, int out_size, void* d_ws, size_t ws_size,
                              hipStream_t stream) {
  const float* x  = (const float*)d_in[0];
  const float* cw = (const float*)d_in[1];
  const float* sc = (const float*)d_in[2];
  float* out = (float*)d_out;
  float* ws  = (float*)d_ws;
  const int B = in_sizes[0] / (D_ * NTOT);   // 16
  if (ws_size >= PART_BYTES + 256) {
    int* cnt = (int*)((char*)d_ws + PART_BYTES);
    hipMemsetAsync(cnt, 0, 64, stream);
    enc_kernel<1><<<dim3(B * 32), dim3(256), 0, stream>>>(x, cw, sc, ws, cnt, out);
  } else {
    enc_kernel<0><<<dim3(B * 32), dim3(256), 0, stream>>>(x, cw, sc, ws, nullptr, out);
    reduce_kernel<<<dim3(B * 4096 / 4 / 256), dim3(256), 0, stream>>>(ws, out);
  }
}

// Round 10
// 82.095 us; speedup vs baseline: 1.8273x; 1.8273x over previous
//
#include <hip/hip_runtime.h>
#include <hip/hip_bf16.h>

// Encoding layer (Deep-TEN). B=16, D=128, K=32, N=H*W=4096.
// E[b,k,d] = sum_n A[b,n,k]*(X[b,n,d]-C[k,d]),  A = softmax_k(scale[k]*||X-C_k||^2)
// x layout: (B, D, H, W) -> X[b,n,d] = x[d*NTOT + n]
//
// R10: revert R9's fused-reduce (device threadfence by all blocks = disaster).
// R8 two-kernel structure + 4 n-tiles per block (grid 256): halves partial
// traffic (4MB), k2 sums 16 partials, C-frags amortized 2x better. Proven
// swizzled bf16 LDS tiles: sNb [n][d] pass1 A-frags, sDb [d][n] pass2
// B-frags, sAb [k][n] A; every MFMA fragment = one ds_read_b128.

#define D_    128
#define K_    32
#define NPB   64
#define NTOT  4096
#define TILES 4          // n-tiles per block
#define BPB   16         // blocks per b  (TILES*NPB*BPB = 4096)

typedef __attribute__((ext_vector_type(8))) short bf16x8;
typedef __attribute__((ext_vector_type(4))) float f32x4;
typedef __attribute__((ext_vector_type(4))) short short4v;

__device__ __forceinline__ short f2b(float f) {
  return (short)__builtin_bit_cast(unsigned short, __float2bfloat16(f));
}

__global__ __launch_bounds__(256, 2) void enc_kernel(
    const float* __restrict__ x,
    const float* __restrict__ cw,
    const float* __restrict__ scale,
    float* __restrict__ ws)
{
  __shared__ __align__(16) short sNb[NPB * D_];  // bf16 X [n][d] swz, 16 KB
  __shared__ __align__(16) short sDb[D_ * NPB];  // bf16 X [d][n] swz, 16 KB
  __shared__ __align__(16) short sAb[K_ * NPB];  // bf16 A [k][n] swz, 4 KB
  __shared__ __align__(16) float sX2w[NPB * 4];
  __shared__ float sasum[K_];

  const int t  = threadIdx.x;
  const int w  = t >> 6;
  const int l  = t & 63;
  const int lr = l & 15;
  const int lg = l >> 4;
  const int b  = blockIdx.x >> 4;               // BPB blocks per b
  const int nbase = (blockIdx.x & (BPB - 1)) * (TILES * NPB);

  const int n4s = t & 15;
  const int d0  = (t >> 4) * 8;
  const float* xb = x + (size_t)b * D_ * NTOT + nbase;

  // ---- resident pass1 B-frags: C^T bf16 + exact c2 (C first: FIFO vmcnt,
  // C drains early so its VALU overlaps the x-tile flight) ----
  bf16x8 bC[2][4];
  float c2p0 = 0.f, c2p1 = 0.f;
  #pragma unroll
  for (int kt = 0; kt < 2; ++kt) {
    const float* crow = cw + (lr + 16 * kt) * D_ + lg * 8;
    #pragma unroll
    for (int s = 0; s < 4; ++s) {
      float4 v0 = *reinterpret_cast<const float4*>(crow + 32 * s);
      float4 v1 = *reinterpret_cast<const float4*>(crow + 32 * s + 4);
      float vv[8] = {v0.x, v0.y, v0.z, v0.w, v1.x, v1.y, v1.z, v1.w};
      bf16x8 f;
      float cs = 0.f;
      #pragma unroll
      for (int j = 0; j < 8; ++j) { f[j] = f2b(vv[j]); cs = fmaf(vv[j], vv[j], cs); }
      bC[kt][s] = f;
      if (kt == 0) c2p0 += cs; else c2p1 += cs;
    }
  }
  c2p0 += __shfl_xor(c2p0, 16); c2p0 += __shfl_xor(c2p0, 32);
  c2p1 += __shfl_xor(c2p1, 16); c2p1 += __shfl_xor(c2p1, 32);
  const float sc0 = scale[lr];
  const float sc1 = scale[lr + 16];

  // ---- prologue: load + stage tile 0 ----
  float4 xs[8];
  #pragma unroll
  for (int j = 0; j < 8; ++j)
    xs[j] = *reinterpret_cast<const float4*>(xb + (size_t)(d0 + j) * NTOT + n4s * 4);
  if (t < K_) sasum[t] = 0.0f;

  #define STAGE_TILE()                                                        \
  {                                                                           \
    short xb16[8][4];                                                         \
    _Pragma("unroll")                                                         \
    for (int j = 0; j < 8; ++j) {                                             \
      xb16[j][0] = f2b(xs[j].x); xb16[j][1] = f2b(xs[j].y);                   \
      xb16[j][2] = f2b(xs[j].z); xb16[j][3] = f2b(xs[j].w);                   \
    }                                                                         \
    float p2[4] = {0.f, 0.f, 0.f, 0.f};                                       \
    _Pragma("unroll")                                                         \
    for (int j = 0; j < 8; ++j) {                                             \
      p2[0] = fmaf(xs[j].x, xs[j].x, p2[0]);                                  \
      p2[1] = fmaf(xs[j].y, xs[j].y, p2[1]);                                  \
      p2[2] = fmaf(xs[j].z, xs[j].z, p2[2]);                                  \
      p2[3] = fmaf(xs[j].w, xs[j].w, p2[3]);                                  \
    }                                                                         \
    _Pragma("unroll")                                                         \
    for (int i = 0; i < 4; ++i) {                                             \
      p2[i] += __shfl_xor(p2[i], 16);                                         \
      p2[i] += __shfl_xor(p2[i], 32);                                         \
    }                                                                         \
    if (lg == 0) {                                                            \
      _Pragma("unroll")                                                       \
      for (int i = 0; i < 4; ++i) sX2w[(n4s * 4 + i) * 4 + w] = p2[i];        \
    }                                                                         \
    _Pragma("unroll")                                                         \
    for (int i = 0; i < 4; ++i) {                                             \
      int n = n4s * 4 + i;                                                    \
      bf16x8 pk;                                                              \
      _Pragma("unroll")                                                       \
      for (int j = 0; j < 8; ++j) pk[j] = xb16[j][i];                         \
      int phys = ((d0 >> 3) ^ (n & 15)) & 15;                                 \
      *reinterpret_cast<bf16x8*>(&sNb[n * D_ + phys * 8]) = pk;               \
    }                                                                         \
    _Pragma("unroll")                                                         \
    for (int j = 0; j < 8; ++j) {                                             \
      int d = d0 + j;                                                         \
      int phys = ((n4s >> 1) ^ (d & 7) ^ ((d >> 3) & 7)) & 7;                 \
      short4v pk4 = {xb16[j][0], xb16[j][1], xb16[j][2], xb16[j][3]};         \
      *reinterpret_cast<short4v*>(&sDb[d * NPB + phys * 8 + (n4s & 1) * 4]) = pk4; \
    }                                                                         \
  }

  STAGE_TILE();
  __syncthreads();

  const int m0 = w * 16;
  const int nrow = m0 + lr;
  f32x4 acc[2][2];
  float asvT[2][4];
  #pragma unroll
  for (int mt = 0; mt < 2; ++mt) {
    #pragma unroll
    for (int dti = 0; dti < 2; ++dti) acc[mt][dti] = (f32x4){0.f, 0.f, 0.f, 0.f};
    #pragma unroll
    for (int r = 0; r < 4; ++r) asvT[mt][r] = 0.f;
  }

  #pragma unroll
  for (int tile = 0; tile < TILES; ++tile) {
    if (tile < TILES - 1) {              // prefetch next tile: in flight under compute
      #pragma unroll
      for (int j = 0; j < 8; ++j)
        xs[j] = *reinterpret_cast<const float4*>(
            xb + (tile + 1) * NPB + (size_t)(d0 + j) * NTOT + n4s * 4);
    }

    // ---- pass 1: xc tile [16n x 32k] per wave ----
    f32x4 p0 = {0.f, 0.f, 0.f, 0.f}, p1 = {0.f, 0.f, 0.f, 0.f};
    #pragma unroll
    for (int s = 0; s < 4; ++s) {
      int dblk = 4 * s + lg;
      bf16x8 af = *reinterpret_cast<const bf16x8*>(
          &sNb[nrow * D_ + ((dblk ^ lr) & 15) * 8]);
      p0 = __builtin_amdgcn_mfma_f32_16x16x32_bf16(af, bC[0][s], p0, 0, 0, 0);
      p1 = __builtin_amdgcn_mfma_f32_16x16x32_bf16(af, bC[1][s], p1, 0, 0, 0);
    }
    float x2r[4];
    #pragma unroll
    for (int r = 0; r < 4; ++r) {
      float4 v = *reinterpret_cast<const float4*>(&sX2w[(m0 + lg * 4 + r) * 4]);
      x2r[r] = (v.x + v.y) + (v.z + v.w);
    }

    // ---- softmax over K=32 in-register ----
    float a0[4], a1[4], mr[4], sr[4];
    #pragma unroll
    for (int r = 0; r < 4; ++r) {
      float sl0 = sc0 * (x2r[r] - 2.f * p0[r] + c2p0);
      float sl1 = sc1 * (x2r[r] - 2.f * p1[r] + c2p1);
      a0[r] = sl0; a1[r] = sl1;
      mr[r] = fmaxf(sl0, sl1);
    }
    #pragma unroll
    for (int dlt = 1; dlt <= 8; dlt <<= 1)
      #pragma unroll
      for (int r = 0; r < 4; ++r) mr[r] = fmaxf(mr[r], __shfl_xor(mr[r], dlt));
    #pragma unroll
    for (int r = 0; r < 4; ++r) {
      a0[r] = __expf(a0[r] - mr[r]);
      a1[r] = __expf(a1[r] - mr[r]);
      sr[r] = a0[r] + a1[r];
    }
    #pragma unroll
    for (int dlt = 1; dlt <= 8; dlt <<= 1)
      #pragma unroll
      for (int r = 0; r < 4; ++r) sr[r] += __shfl_xor(sr[r], dlt);
    #pragma unroll
    for (int r = 0; r < 4; ++r) {
      float inv = 1.0f / sr[r];
      a0[r] *= inv; a1[r] *= inv;
    }

    // ---- block asum + A -> bf16 LDS tile ----
    float as0 = a0[0] + a0[1] + a0[2] + a0[3];
    float as1 = a1[0] + a1[1] + a1[2] + a1[3];
    as0 += __shfl_xor(as0, 16); as0 += __shfl_xor(as0, 32);
    as1 += __shfl_xor(as1, 16); as1 += __shfl_xor(as1, 32);
    if (lg == 0) {
      atomicAdd(&sasum[lr], as0);
      atomicAdd(&sasum[lr + 16], as1);
    }
    #pragma unroll
    for (int r = 0; r < 4; ++r) {
      int n = m0 + lg * 4 + r;
      sAb[lr * 64 + (n ^ ((lr & 7) << 3))] = f2b(a0[r]);
      sAb[(lr + 16) * 64 + (n ^ (((lr + 16) & 7) << 3))] = f2b(a1[r]);
    }
    __syncthreads();

    // ---- pass 2 accumulate: E += A^T X ----
    bf16x8 aA[2][2];
    #pragma unroll
    for (int mt = 0; mt < 2; ++mt) {
      int k = mt * 16 + lr;
      #pragma unroll
      for (int s = 0; s < 2; ++s) {
        int nb = 32 * s + lg * 8;
        aA[mt][s] = *reinterpret_cast<const bf16x8*>(
            &sAb[k * 64 + (nb ^ ((k & 7) << 3))]);
      }
    }
    #pragma unroll
    for (int mt = 0; mt < 2; ++mt)
      #pragma unroll
      for (int r = 0; r < 4; ++r) asvT[mt][r] += sasum[mt * 16 + lg * 4 + r];
    #pragma unroll
    for (int s = 0; s < 2; ++s) {
      #pragma unroll
      for (int dti = 0; dti < 2; ++dti) {
        int d = (2 * w + dti) * 16 + lr;
        int phys = (((4 * s + lg) ^ (d & 7) ^ ((d >> 3) & 7)) & 7);
        bf16x8 bf = *reinterpret_cast<const bf16x8*>(&sDb[d * NPB + phys * 8]);
        acc[0][dti] = __builtin_amdgcn_mfma_f32_16x16x32_bf16(aA[0][s], bf, acc[0][dti], 0, 0, 0);
        acc[1][dti] = __builtin_amdgcn_mfma_f32_16x16x32_bf16(aA[1][s], bf, acc[1][dti], 0, 0, 0);
      }
    }
    __syncthreads();                      // LDS free for next tile

    if (tile < TILES - 1) {
      if (t < K_) sasum[t] = 0.0f;
      STAGE_TILE();
      __syncthreads();
    }
  }

  // ---- epilogue: -asum*C correction + plain coalesced store to workspace ----
  float* wp = ws + (size_t)blockIdx.x * (K_ * D_);
  #pragma unroll
  for (int mt = 0; mt < 2; ++mt)
    #pragma unroll
    for (int dti = 0; dti < 2; ++dti) {
      int d = (2 * w + dti) * 16 + lr;
      #pragma unroll
      for (int r = 0; r < 4; ++r) {
        int k = mt * 16 + lg * 4 + r;
        wp[k * D_ + d] = acc[mt][dti][r] - asvT[mt][r] * cw[k * D_ + d];
      }
    }
}

// out[b][kd] = sum_{p<16} ws[b*16+p][kd]; 4 floats per thread, coalesced.
__global__ __launch_bounds__(256) void reduce_kernel(
    const float* __restrict__ ws, float* __restrict__ out)
{
  int g = blockIdx.x * 256 + threadIdx.x;       // B*1024 threads
  int b = g >> 10;                              // 1024 float4 per b
  int q = g & 1023;
  const float4* base = reinterpret_cast<const float4*>(ws) + (size_t)b * BPB * 1024 + q;
  float4 s = {0.f, 0.f, 0.f, 0.f};
  #pragma unroll
  for (int p = 0; p < BPB; ++p) {
    float4 v = base[(size_t)p * 1024];
    s.x += v.x; s.y += v.y; s.z += v.z; s.w += v.w;
  }
  reinterpret_cast<float4*>(out)[g] = s;
}

extern "C" void kernel_launch(void* const* d_in, const int* in_sizes, int n_in,
                              void* d_out, int out_size, void* d_ws, size_t ws_size,
                              hipStream_t stream) {
  const float* x  = (const float*)d_in[0];
  const float* cw = (const float*)d_in[1];
  const float* sc = (const float*)d_in[2];
  float* out = (float*)d_out;
  float* ws  = (float*)d_ws;
  const int B = in_sizes[0] / (D_ * NTOT);   // 16
  enc_kernel<<<dim3(B * BPB), dim3(256), 0, stream>>>(x, cw, sc, ws);
  reduce_kernel<<<dim3(B * 1024 / 256), dim3(256), 0, stream>>>(ws, out);
}